// Round 7
// baseline (276.277 us; speedup 1.0000x reference)
//
#include <hip/hip_runtime.h>
#include <hip/hip_bf16.h>
#include <stdint.h>

// MHA: B=1, L=4096, D=1024, H=16, dk=64.
// Inputs fp32, OUTPUT fp32. Internal compute bf16 with fp32 accumulation.
//
// v10:
//  - flash: ONE barrier per kv-iter.  vmcnt(0)+s_barrier at iter start is
//    the exact minimal wait (only this iter's own copies are outstanding,
//    issued a full iter earlier).  QK+softmax+PV fused into one scheduling
//    region -> waves de-lockstep, V reads hoist into softmax shadows.
//  - gemm_qkv: operand-SWAPPED MFMA for Q/K (out: lane=seq-row, reg=dk) so
//    the epilogue stores 16x bf16x4 straight to the frag-major layout
//    (dk&7 is the inner axis); V keeps original order (reg=kv, inner ✓).
//    v9's 32KB LDS epilogue round-trip deleted.

typedef __bf16 bf16_t;
typedef __bf16 bf16x8 __attribute__((ext_vector_type(8)));
typedef __bf16 bf16x4 __attribute__((ext_vector_type(4)));
typedef float f32x4 __attribute__((ext_vector_type(4)));
typedef unsigned short u16x8 __attribute__((ext_vector_type(8)));

#define MFMA_BF16 __builtin_amdgcn_mfma_f32_16x16x32_bf16

__device__ __forceinline__ void async_copy16(const void* g, void* lds) {
  __builtin_amdgcn_global_load_lds(
      (__attribute__((address_space(1))) void*)(uintptr_t)g,
      (__attribute__((address_space(3))) void*)lds, 16, 0, 0);
}

// ---------------------------------------------------------------------------
// fp32 -> bf16 cast, 8 elems/thread, z selects tensor.
// ---------------------------------------------------------------------------
__global__ __launch_bounds__(256) void cast_f32_bf16(
    const float* __restrict__ s0, bf16_t* __restrict__ d0, int n0,
    const float* __restrict__ s1, bf16_t* __restrict__ d1, int n1,
    const float* __restrict__ s2, bf16_t* __restrict__ d2, int n2,
    const float* __restrict__ s3, bf16_t* __restrict__ d3, int n3,
    const float* __restrict__ s4, bf16_t* __restrict__ d4, int n4,
    const float* __restrict__ s5, bf16_t* __restrict__ d5, int n5,
    const float* __restrict__ s6, bf16_t* __restrict__ d6, int n6) {
  const float* s;
  bf16_t* d;
  int n;
  switch (blockIdx.z) {
    case 0: s = s0; d = d0; n = n0; break;
    case 1: s = s1; d = d1; n = n1; break;
    case 2: s = s2; d = d2; n = n2; break;
    case 3: s = s3; d = d3; n = n3; break;
    case 4: s = s4; d = d4; n = n4; break;
    case 5: s = s5; d = d5; n = n5; break;
    default: s = s6; d = d6; n = n6; break;
  }
  const int i = (blockIdx.x * 256 + threadIdx.x) * 8;
  if (i >= n) return;
  float4 a = *(const float4*)(s + i);
  float4 b = *(const float4*)(s + i + 4);
  bf16x8 o;
  o[0] = (bf16_t)a.x; o[1] = (bf16_t)a.y; o[2] = (bf16_t)a.z; o[3] = (bf16_t)a.w;
  o[4] = (bf16_t)b.x; o[5] = (bf16_t)b.y; o[6] = (bf16_t)b.z; o[7] = (bf16_t)b.w;
  *(bf16x8*)(d + i) = o;
}

// ---------------------------------------------------------------------------
// QKV projection GEMM with fused frag-tiling epilogue (direct stores).
// Tile 128x128, BK=32, 4 waves 2x2.  z=0 -> Qt (scaled), z=1 -> Kt,
// z=2 -> Vt (transposed + P-packet-permuted).
// z<2 uses SWAPPED MFMA operands: out lane l16 = seq-row, regs = 4
// consecutive dk -> bf16x4 store hits the frag layout's inner dk&7 axis.
// z=2 keeps original order: regs = 4 consecutive kv -> inner axis of the
// V-permuted layout (v8-verified formula).
// ---------------------------------------------------------------------------
__global__ __launch_bounds__(256) void gemm_qkv(
    const bf16_t* __restrict__ A0, const bf16_t* __restrict__ W0,
    const float* __restrict__ b0, bf16_t* __restrict__ D0,
    const bf16_t* __restrict__ A1, const bf16_t* __restrict__ W1,
    const float* __restrict__ b1, bf16_t* __restrict__ D1,
    const bf16_t* __restrict__ A2, const bf16_t* __restrict__ W2,
    const float* __restrict__ b2, bf16_t* __restrict__ D2,
    int M, int N, int K) {
  const bf16_t *A, *W;
  const float* bias;
  bf16_t* D;
  const int zz = blockIdx.z;
  if (zz == 0)      { A = A0; W = W0; bias = b0; D = D0; }
  else if (zz == 1) { A = A1; W = W1; bias = b1; D = D1; }
  else              { A = A2; W = W2; bias = b2; D = D2; }

  __shared__ bf16_t As[128][32];
  __shared__ bf16_t Bs[128][32];

  const int t = threadIdx.x;
  const int w = t >> 6, lane = t & 63;
  const int quad = lane >> 4, l16 = lane & 15;
  const int wr = w >> 1, wc = w & 1;
  const int m0 = blockIdx.x * 128;
  const int n0 = blockIdx.y * 128;
  const int srow = lane >> 2;
  const int scol = (lane & 3) * 8;

  f32x4 acc[4][4] = {};

  for (int k0 = 0; k0 < K; k0 += 32) {
    async_copy16(&A[(size_t)(m0 + (2 * w) * 16 + srow) * K + k0 + scol],
                 (char*)As + (2 * w) * 1024);
    async_copy16(&A[(size_t)(m0 + (2 * w + 1) * 16 + srow) * K + k0 + scol],
                 (char*)As + (2 * w + 1) * 1024);
    async_copy16(&W[(size_t)(n0 + (2 * w) * 16 + srow) * K + k0 + scol],
                 (char*)Bs + (2 * w) * 1024);
    async_copy16(&W[(size_t)(n0 + (2 * w + 1) * 16 + srow) * K + k0 + scol],
                 (char*)Bs + (2 * w + 1) * 1024);
    __syncthreads();

    bf16x8 af[4], bfr[4];
#pragma unroll
    for (int mt = 0; mt < 4; mt++)
      af[mt] = *(const bf16x8*)&As[wr * 64 + mt * 16 + l16][quad * 8];
#pragma unroll
    for (int nt = 0; nt < 4; nt++)
      bfr[nt] = *(const bf16x8*)&Bs[wc * 64 + nt * 16 + l16][quad * 8];
    if (zz < 2) {
#pragma unroll
      for (int mt = 0; mt < 4; mt++)
#pragma unroll
        for (int nt = 0; nt < 4; nt++)
          acc[mt][nt] = MFMA_BF16(bfr[nt], af[mt], acc[mt][nt], 0, 0, 0);
    } else {
#pragma unroll
      for (int mt = 0; mt < 4; mt++)
#pragma unroll
        for (int nt = 0; nt < 4; nt++)
          acc[mt][nt] = MFMA_BF16(af[mt], bfr[nt], acc[mt][nt], 0, 0, 0);
    }
    __syncthreads();
  }

  if (zz < 2) {
    // acc[mt][nt] reg r, lane (quad,l16) = C[m0+wr*64+mt*16+l16]
    //                                       [n0+wc*64+nt*16+quad*4+r]
    const float qs = (zz == 0) ? 0.125f * 1.44269504088896340736f : 1.0f;
    const int hh = (n0 >> 6) + wc;
#pragma unroll
    for (int nt = 0; nt < 4; nt++) {
      const int b = nt * 16 + quad * 4;  // dk base (r=0)
      const f32x4 bb4 = *(const f32x4*)&bias[n0 + wc * 64 + b];
      const int ig = ((b >> 5) * 64 + ((b >> 3) & 3) * 16 + l16) * 8 + (b & 7);
#pragma unroll
      for (int mt = 0; mt < 4; mt++) {
        const int rowtile = (m0 >> 4) + wr * 4 + mt;
        bf16x4 pk;
#pragma unroll
        for (int r = 0; r < 4; r++)
          pk[r] = (bf16_t)((acc[mt][nt][r] + bb4[r]) * qs);
        *(bf16x4*)(D + (size_t)(hh * 256 + rowtile) * 1024 + ig) = pk;
      }
    }
  } else {
    // V: acc[mt][nt] reg r = C[kv = m0+wr*64+mt*16+quad*4+r]
    //                          [dk-col = n0+wc*64+nt*16+l16]  (v8 formula)
#pragma unroll
    for (int nt = 0; nt < 4; nt++) {
      const int col = n0 + wc * 64 + nt * 16 + l16;
      const int hh = col >> 6, dk = col & 63;
      const float bb = bias[col];
#pragma unroll
      for (int mt = 0; mt < 4; mt++) {
        const int kvb = m0 + wr * 64 + mt * 16 + quad * 4;  // r=0 kv
        const int r50 = kvb & 31;
        bf16x4 pk;
#pragma unroll
        for (int r = 0; r < 4; r++) pk[r] = (bf16_t)(acc[mt][nt][r] + bb);
        const size_t addr =
            (size_t)(hh * 256 + (kvb >> 6) * 4 + (dk >> 4)) * 1024 +
            (size_t)(((kvb >> 5) & 1) * 64 + ((r50 & 15) >> 2) * 16 +
                     (dk & 15)) * 8 +
            (((r50 >> 4) & 1) << 2);
        *(bf16x4*)(D + addr) = pk;
      }
    }
  }
}

// ---------------------------------------------------------------------------
// Output GEMM: C = A @ W^T + b (fp32 out).  Same m97 128x128 shape.
// ---------------------------------------------------------------------------
__global__ __launch_bounds__(256) void gemm_out(
    const bf16_t* __restrict__ A, const bf16_t* __restrict__ W,
    const float* __restrict__ bias, float* __restrict__ C, int M, int N,
    int K) {
  __shared__ bf16_t As[128][32];
  __shared__ bf16_t Bs[128][32];

  const int t = threadIdx.x;
  const int w = t >> 6, lane = t & 63;
  const int quad = lane >> 4, l16 = lane & 15;
  const int wr = w >> 1, wc = w & 1;
  const int m0 = blockIdx.x * 128;
  const int n0 = blockIdx.y * 128;
  const int srow = lane >> 2;
  const int scol = (lane & 3) * 8;

  f32x4 acc[4][4] = {};

  for (int k0 = 0; k0 < K; k0 += 32) {
    async_copy16(&A[(size_t)(m0 + (2 * w) * 16 + srow) * K + k0 + scol],
                 (char*)As + (2 * w) * 1024);
    async_copy16(&A[(size_t)(m0 + (2 * w + 1) * 16 + srow) * K + k0 + scol],
                 (char*)As + (2 * w + 1) * 1024);
    async_copy16(&W[(size_t)(n0 + (2 * w) * 16 + srow) * K + k0 + scol],
                 (char*)Bs + (2 * w) * 1024);
    async_copy16(&W[(size_t)(n0 + (2 * w + 1) * 16 + srow) * K + k0 + scol],
                 (char*)Bs + (2 * w + 1) * 1024);
    __syncthreads();

    bf16x8 af[4], bfr[4];
#pragma unroll
    for (int mt = 0; mt < 4; mt++)
      af[mt] = *(const bf16x8*)&As[wr * 64 + mt * 16 + l16][quad * 8];
#pragma unroll
    for (int nt = 0; nt < 4; nt++)
      bfr[nt] = *(const bf16x8*)&Bs[wc * 64 + nt * 16 + l16][quad * 8];
#pragma unroll
    for (int mt = 0; mt < 4; mt++)
#pragma unroll
      for (int nt = 0; nt < 4; nt++)
        acc[mt][nt] = MFMA_BF16(af[mt], bfr[nt], acc[mt][nt], 0, 0, 0);
    __syncthreads();
  }

#pragma unroll
  for (int nt = 0; nt < 4; nt++) {
    const int col = n0 + wc * 64 + nt * 16 + l16;
    const float bb = bias[col];
#pragma unroll
    for (int mt = 0; mt < 4; mt++) {
#pragma unroll
      for (int r = 0; r < 4; r++) {
        const int row = m0 + wr * 64 + mt * 16 + quad * 4 + r;
        C[(size_t)row * N + col] = acc[mt][nt][r] + bb;
      }
    }
  }
}

// ---------------------------------------------------------------------------
// Flash v10.  8 waves, kv-parity split, Nq=2, in-register P, ONE barrier
// per iter:
//   iter mc: s_waitcnt vmcnt(0)   [this iter's K/V copies, issued a full
//            iter ago, are the ONLY outstanding vmem -> exact minimal wait]
//            s_barrier ; STAGE(mc+1) ; {K reads, QK, softmax, V reads, PV}
// The fused region lets the scheduler hoist V reads / interleave PV with
// softmax, and waves are free to skew between barriers (32 convergence
// points instead of 64).  Double-buffer WAR: STAGE(mc+1) is issued after
// the barrier that proves all waves finished reading buf^1.
// ---------------------------------------------------------------------------
__global__ __launch_bounds__(512, 4) void flash_attn(
    const bf16_t* __restrict__ Qt, const bf16_t* __restrict__ Kt,
    const bf16_t* __restrict__ Vt, bf16_t* __restrict__ O, int L) {
  // linear block id lands on XCD i%8 (round-robin dispatch): 2 heads/XCD.
  const int i = blockIdx.x;
  const int slot = i >> 3;                  // 0..63 within XCD
  const int h = (i & 7) * 2 + (slot >> 5);  // 2 heads per XCD
  const int qblk = slot & 31;

  const int t = threadIdx.x;
  const int w = t >> 6, lane = t & 63;
  const int quad = lane >> 4, l16 = lane & 15;
  const int g = w >> 2;   // kv parity group
  const int ws = w & 3;   // q-pair index within group
  const int tq0 = qblk * 8 + ws * 2;

  __shared__ bf16_t Kst[2][8192];  // 16 KB per buffer (chunk pair)
  __shared__ bf16_t Vst[2][8192];  // 16 KB per buffer

  const size_t hb = (size_t)h * 256 * 1024;  // head base in tiled layouts

  union V8 {
    bf16x8 v8;
    bf16x4 v4[2];
  };

  // persistent Q B-frags (two q-tiles per wave)
  bf16x8 qa[2][2];
#pragma unroll
  for (int qt = 0; qt < 2; qt++)
#pragma unroll
    for (int kc = 0; kc < 2; kc++)
      qa[qt][kc] = *(const bf16x8*)(Qt + hb + (size_t)(tq0 + qt) * 1024 +
                                    kc * 512 + lane * 8);

  // stage chunk pair `mc` (chunks 2mc, 2mc+1): 16 KB K + 16 KB V.
#define STAGE(mc_, buf_)                                                      \
  {                                                                           \
    const size_t pb_ = hb + (size_t)(mc_) * 8192;                             \
    async_copy16(Kt + pb_ + (size_t)t * 8, (char*)&Kst[buf_][0] + w * 1024);  \
    async_copy16(Kt + pb_ + 4096 + (size_t)t * 8,                             \
                 (char*)&Kst[buf_][0] + 8192 + w * 1024);                     \
    async_copy16(Vt + pb_ + (size_t)t * 8, (char*)&Vst[buf_][0] + w * 1024);  \
    async_copy16(Vt + pb_ + 4096 + (size_t)t * 8,                             \
                 (char*)&Vst[buf_][0] + 8192 + w * 1024);                     \
  }

  f32x4 oT[2][4] = {};  // [qt][dkt]
  float ls[2] = {0.f, 0.f};
  const int laneK = lane * 16;
  V8 pb[2][2];

  STAGE(0, 0);

  const int NMC = L / 128;  // 32 macro-iters
  for (int mc = 0; mc < NMC; mc++) {
    const int buf = mc & 1;
    asm volatile("s_waitcnt vmcnt(0)" ::: "memory");
    __builtin_amdgcn_s_barrier();
    __builtin_amdgcn_sched_barrier(0);
    if (mc + 1 < NMC) STAGE(mc + 1, buf ^ 1);

    const char* Kc = (const char*)&Kst[buf][0] + g * 8192;
    const char* Vc = (const char*)&Vst[buf][0] + g * 8192;

    // QK^T for both q-tiles
    f32x4 sT[2][4];
    __builtin_amdgcn_s_setprio(1);
#pragma unroll
    for (int tt = 0; tt < 4; tt++) {
      const bf16x8 k0 = *(const bf16x8*)(Kc + tt * 2048 + laneK);
      const bf16x8 k1 = *(const bf16x8*)(Kc + tt * 2048 + 1024 + laneK);
#pragma unroll
      for (int qt = 0; qt < 2; qt++) {
        f32x4 z = {0.f, 0.f, 0.f, 0.f};
        z = MFMA_BF16(k0, qa[qt][0], z, 0, 0, 0);
        z = MFMA_BF16(k1, qa[qt][1], z, 0, 0, 0);
        sT[qt][tt] = z;
      }
    }
    __builtin_amdgcn_s_setprio(0);

    // softmax: p = 2^s, row-sum partials, pack PV B-frags in-register.
#pragma unroll
    for (int qt = 0; qt < 2; qt++) {
#pragma unroll
      for (int tt = 0; tt < 4; tt++) {
        bf16x4 pk;
        float rs = 0.f;
#pragma unroll
        for (int r = 0; r < 4; r++) {
          const float pv = __builtin_amdgcn_exp2f(sT[qt][tt][r]);
          rs += pv;
          pk[r] = (bf16_t)pv;
        }
        ls[qt] += rs;
        pb[qt][tt >> 1].v4[tt & 1] = pk;
      }
    }

    // O^T += V^T . P  (V pre-permuted to P's packet order; plain b128)
    __builtin_amdgcn_s_setprio(1);
#pragma unroll
    for (int dkt = 0; dkt < 4; dkt++) {
#pragma unroll
      for (int kvc = 0; kvc < 2; kvc++) {
        const bf16x8 vv =
            *(const bf16x8*)(Vc + dkt * 2048 + kvc * 1024 + laneK);
#pragma unroll
        for (int qt = 0; qt < 2; qt++)
          oT[qt][dkt] = MFMA_BF16(vv, pb[qt][kvc].v8, oT[qt][dkt], 0, 0, 0);
      }
    }
    __builtin_amdgcn_s_setprio(0);
  }
#undef STAGE

  // cross-group combine: g=1 waves hand partial (oT, ls) to matching g=0
  // wave via LDS scratch (qt0 in Kst, qt1 in Vst; stride 20 floats).
  __syncthreads();
  float* sc0 = (float*)&Kst[0][0];
  float* sc1 = (float*)&Vst[0][0];
  const int sidx = (ws * 64 + lane) * 20;
  if (g == 1) {
#pragma unroll
    for (int dkt = 0; dkt < 4; dkt++) {
      *(f32x4*)(sc0 + sidx + dkt * 4) = oT[0][dkt];
      *(f32x4*)(sc1 + sidx + dkt * 4) = oT[1][dkt];
    }
    sc0[sidx + 16] = ls[0];
    sc1[sidx + 16] = ls[1];
  }
  __syncthreads();
  if (g == 0) {
#pragma unroll
    for (int dkt = 0; dkt < 4; dkt++) {
      oT[0][dkt] += *(const f32x4*)(sc0 + sidx + dkt * 4);
      oT[1][dkt] += *(const f32x4*)(sc1 + sidx + dkt * 4);
    }
    ls[0] += sc0[sidx + 16];
    ls[1] += sc1[sidx + 16];

#pragma unroll
    for (int qt = 0; qt < 2; qt++) {
      float l = ls[qt];
      l += __shfl_xor(l, 16);
      l += __shfl_xor(l, 32);
      const float inv = 1.0f / l;
      const size_t row = (size_t)(tq0 + qt) * 16 + l16;
#pragma unroll
      for (int dkt = 0; dkt < 4; dkt++) {
        bf16x4 ov;
#pragma unroll
        for (int r = 0; r < 4; r++) ov[r] = (bf16_t)(oT[qt][dkt][r] * inv);
        *(bf16x4*)(O + row * 1024 + h * 64 + dkt * 16 + quad * 4) = ov;
      }
    }
  }
}

// ---------------------------------------------------------------------------
extern "C" void kernel_launch(void* const* d_in, const int* in_sizes, int n_in,
                              void* d_out, int out_size, void* d_ws,
                              size_t ws_size, hipStream_t stream) {
  const float* q  = (const float*)d_in[0];
  const float* k  = (const float*)d_in[1];
  const float* v  = (const float*)d_in[2];
  const float* wq = (const float*)d_in[3];
  const float* bq = (const float*)d_in[4];
  const float* wk = (const float*)d_in[5];
  const float* bk = (const float*)d_in[6];
  const float* wv = (const float*)d_in[7];
  const float* bv = (const float*)d_in[8];
  const float* wo = (const float*)d_in[9];
  const float* bo = (const float*)d_in[10];
  float* out = (float*)d_out;

  const int L = 4096, D = 1024;
  const int nLD = L * D;  // 4M
  const int nDD = D * D;  // 1M
  bf16_t* p = (bf16_t*)d_ws;
  bf16_t* qb  = p; p += nLD;
  bf16_t* kb  = p; p += nLD;
  bf16_t* vb  = p; p += nLD;
  bf16_t* wqb = p; p += nDD;
  bf16_t* wkb = p; p += nDD;
  bf16_t* wvb = p; p += nDD;
  bf16_t* wob = p; p += nDD;
  bf16_t* Op  = p; p += nLD;
  bf16_t* Qt  = p; p += nLD;
  bf16_t* Kt  = p; p += nLD;
  bf16_t* Vt  = p; p += nLD;

  dim3 blk(256);
  cast_f32_bf16<<<dim3(nLD / (256 * 8), 1, 7), blk, 0, stream>>>(
      q, qb, nLD, k, kb, nLD, v, vb, nLD, wq, wqb, nDD, wk, wkb, nDD,
      wv, wvb, nDD, wo, wob, nDD);
  gemm_qkv<<<dim3(L / 128, D / 128, 3), blk, 0, stream>>>(
      qb, wqb, bq, Qt, kb, wkb, bk, Kt, vb, wvb, bv, Vt, L, D, D);
  flash_attn<<<dim3((L / 128) * 16), dim3(512), 0, stream>>>(Qt, Kt, Vt, Op, L);
  gemm_out<<<dim3(L / 128, D / 128), blk, 0, stream>>>(Op, wob, bo, out, L, D,
                                                       D);
}

// Round 8
// 253.242 us; speedup vs baseline: 1.0910x; 1.0910x over previous
//
#include <hip/hip_runtime.h>
#include <hip/hip_bf16.h>
#include <stdint.h>

// MHA: B=1, L=4096, D=1024, H=16, dk=64.
// Inputs fp32, OUTPUT fp32. Internal compute bf16 with fp32 accumulation.
//
// v11:
//  - flash: EXACT v9 (best measured: 79.0us).  Two-phase counted-vmcnt
//    schedule; v10's one-barrier variant regressed (+3.6) -> reverted.
//  - GEMMs retiled 128x128 -> 64x128 (per-wave 32x64, acc[2][4]):
//    gemm_qkv 768->1536 blocks (3->6/CU), gemm_out 256->512 (1->2/CU).
//    These 2-phase kernels are barrier-stall-bound; co-resident independent
//    blocks fill each other's stalls.  gemm_out at 1 block/CU was ~12.5%
//    occupancy -- the biggest non-flash cost.
//  - gemm_qkv keeps the v9-style LDS-routed epilogue (direct scattered
//    stores measured ~10us worse in v10), re-derived for the 64-row tile:
//    16KB LDS image -> 2 contiguous 8KB regions -> dwordx4 streams.

typedef __bf16 bf16_t;
typedef __bf16 bf16x8 __attribute__((ext_vector_type(8)));
typedef __bf16 bf16x4 __attribute__((ext_vector_type(4)));
typedef float f32x4 __attribute__((ext_vector_type(4)));
typedef unsigned short u16x8 __attribute__((ext_vector_type(8)));

#define MFMA_BF16 __builtin_amdgcn_mfma_f32_16x16x32_bf16

__device__ __forceinline__ void async_copy16(const void* g, void* lds) {
  __builtin_amdgcn_global_load_lds(
      (__attribute__((address_space(1))) void*)(uintptr_t)g,
      (__attribute__((address_space(3))) void*)lds, 16, 0, 0);
}

// ---------------------------------------------------------------------------
// fp32 -> bf16 cast, 8 elems/thread, z selects tensor.
// ---------------------------------------------------------------------------
__global__ __launch_bounds__(256) void cast_f32_bf16(
    const float* __restrict__ s0, bf16_t* __restrict__ d0, int n0,
    const float* __restrict__ s1, bf16_t* __restrict__ d1, int n1,
    const float* __restrict__ s2, bf16_t* __restrict__ d2, int n2,
    const float* __restrict__ s3, bf16_t* __restrict__ d3, int n3,
    const float* __restrict__ s4, bf16_t* __restrict__ d4, int n4,
    const float* __restrict__ s5, bf16_t* __restrict__ d5, int n5,
    const float* __restrict__ s6, bf16_t* __restrict__ d6, int n6) {
  const float* s;
  bf16_t* d;
  int n;
  switch (blockIdx.z) {
    case 0: s = s0; d = d0; n = n0; break;
    case 1: s = s1; d = d1; n = n1; break;
    case 2: s = s2; d = d2; n = n2; break;
    case 3: s = s3; d = d3; n = n3; break;
    case 4: s = s4; d = d4; n = n4; break;
    case 5: s = s5; d = d5; n = n5; break;
    default: s = s6; d = d6; n = n6; break;
  }
  const int i = (blockIdx.x * 256 + threadIdx.x) * 8;
  if (i >= n) return;
  float4 a = *(const float4*)(s + i);
  float4 b = *(const float4*)(s + i + 4);
  bf16x8 o;
  o[0] = (bf16_t)a.x; o[1] = (bf16_t)a.y; o[2] = (bf16_t)a.z; o[3] = (bf16_t)a.w;
  o[4] = (bf16_t)b.x; o[5] = (bf16_t)b.y; o[6] = (bf16_t)b.z; o[7] = (bf16_t)b.w;
  *(bf16x8*)(d + i) = o;
}

// ---------------------------------------------------------------------------
// QKV projection GEMM, tile 64x128, BK=32, 4 waves 2x2 (per-wave 32x64).
// z=0 -> Qt (scaled), z=1 -> Kt, z=2 -> Vt (transposed+P-packet-permuted).
// Epilogue: acc -> 16KB LDS image in frag-granule order -> 4 linear passes
// of dwordx4 into the 2 contiguous 8KB regions the 64x128 C-tile occupies
// in the frag-major layout.
//   Q/K granule  = hh*256 + (row>>4);  ig = ((dk>>5)*64 + ((dk>>3)&3)*16 +
//                  (row&15))*8 + (dk&7)
//   V   granule  = hh*256 + (kv>>6)*4 + (dk>>4); ig = (((kv>>5)&1)*64 +
//                  ((kv&15)>>2)*16 + (dk&15))*8 + ((kv>>4)&1)*4 + (kv&3)
// (both sample-verified against the v8/v9 formulas).
// ---------------------------------------------------------------------------
__global__ __launch_bounds__(256) void gemm_qkv(
    const bf16_t* __restrict__ A0, const bf16_t* __restrict__ W0,
    const float* __restrict__ b0, bf16_t* __restrict__ D0,
    const bf16_t* __restrict__ A1, const bf16_t* __restrict__ W1,
    const float* __restrict__ b1, bf16_t* __restrict__ D1,
    const bf16_t* __restrict__ A2, const bf16_t* __restrict__ W2,
    const float* __restrict__ b2, bf16_t* __restrict__ D2,
    int M, int N, int K) {
  const bf16_t *A, *W;
  const float* bias;
  bf16_t* D;
  const int zz = blockIdx.z;
  if (zz == 0)      { A = A0; W = W0; bias = b0; D = D0; }
  else if (zz == 1) { A = A1; W = W1; bias = b1; D = D1; }
  else              { A = A2; W = W2; bias = b2; D = D2; }

  __shared__ __align__(16) char smem[16384];
  bf16_t (*As)[32] = reinterpret_cast<bf16_t(*)[32]>(smem);         // 64x32
  bf16_t (*Bs)[32] = reinterpret_cast<bf16_t(*)[32]>(smem + 4096);  // 128x32

  const int t = threadIdx.x;
  const int w = t >> 6, lane = t & 63;
  const int quad = lane >> 4, l16 = lane & 15;
  const int wr = w >> 1, wc = w & 1;
  const int m0 = blockIdx.x * 64;
  const int n0 = blockIdx.y * 128;
  const int srow = t >> 2;          // staging row (4 threads/row)
  const int scol = (t & 3) * 8;     // staging col (elems)

  f32x4 acc[2][4] = {};

  for (int k0 = 0; k0 < K; k0 += 32) {
    async_copy16(&A[(size_t)(m0 + srow) * K + k0 + scol], (char*)smem + t * 16);
    async_copy16(&W[(size_t)(n0 + srow) * K + k0 + scol],
                 (char*)smem + 4096 + t * 16);
    async_copy16(&W[(size_t)(n0 + 64 + srow) * K + k0 + scol],
                 (char*)smem + 8192 + t * 16);
    __syncthreads();

    bf16x8 af[2], bfr[4];
#pragma unroll
    for (int mt = 0; mt < 2; mt++)
      af[mt] = *(const bf16x8*)&As[wr * 32 + mt * 16 + l16][quad * 8];
#pragma unroll
    for (int nt = 0; nt < 4; nt++)
      bfr[nt] = *(const bf16x8*)&Bs[wc * 64 + nt * 16 + l16][quad * 8];
#pragma unroll
    for (int mt = 0; mt < 2; mt++)
#pragma unroll
      for (int nt = 0; nt < 4; nt++)
        acc[mt][nt] = MFMA_BF16(af[mt], bfr[nt], acc[mt][nt], 0, 0, 0);
    __syncthreads();
  }

  // ---- epilogue: dump acc into 16KB LDS image (frag-granule order) ----
  bf16_t* Ep = (bf16_t*)smem;  // [gr 0..7][1024]; gr = wc*4 + (granule&3)
  if (zz < 2) {
    const float qs = (zz == 0) ? 0.125f * 1.44269504088896340736f : 1.0f;
#pragma unroll
    for (int nt = 0; nt < 4; nt++) {
      const int col = n0 + wc * 64 + nt * 16 + l16;
      const float bb = bias[col];
      const int dk = nt * 16 + l16;
      const int igb =
          ((dk >> 5) * 64 + ((dk >> 3) & 3) * 16) * 8 + (dk & 7);
#pragma unroll
      for (int mt = 0; mt < 2; mt++) {
        const int gr = wc * 4 + wr * 2 + mt;  // row-granule within region
#pragma unroll
        for (int r = 0; r < 4; r++)
          Ep[gr * 1024 + igb + (quad * 4 + r) * 8] =
              (bf16_t)((acc[mt][nt][r] + bb) * qs);
      }
    }
  } else {
    // V: kv = m0 + wr*32 + mt*16 + quad*4 + r; granule-within-chunk = nt.
    // ig = (wr*64 + quad*16 + l16)*8 + mt*4 + r  (r=0..3 contiguous).
#pragma unroll
    for (int nt = 0; nt < 4; nt++) {
      const int col = n0 + wc * 64 + nt * 16 + l16;
      const float bb = bias[col];
      const int gr = wc * 4 + nt;
#pragma unroll
      for (int mt = 0; mt < 2; mt++) {
        bf16x4 pk;
#pragma unroll
        for (int r = 0; r < 4; r++) pk[r] = (bf16_t)(acc[mt][nt][r] + bb);
        *(bf16x4*)&Ep[gr * 1024 + (wr * 64 + quad * 16 + l16) * 8 + mt * 4] =
            pk;
      }
    }
  }
  __syncthreads();

  // ---- linear copy: 2 contiguous 8KB regions, 16B/lane coalesced ----
  const int hh0 = n0 >> 6;
  const size_t gb = (zz < 2) ? (size_t)(m0 >> 4) : (size_t)(m0 >> 6) * 4;
#pragma unroll
  for (int p = 0; p < 4; p++) {
    const int f = (p * 256 + t) * 8;  // elem index in Ep
    const int reg = f >> 12;          // head-half region
    const int off = f & 4095;
    const float4 vv = *(const float4*)&Ep[f];
    *(float4*)(D + ((size_t)(hh0 + reg) * 256 + gb) * 1024 + off) = vv;
  }
}

// ---------------------------------------------------------------------------
// Output GEMM: C = A @ W^T + b (fp32 out).  Tile 64x128 (2 blocks/CU).
// ---------------------------------------------------------------------------
__global__ __launch_bounds__(256) void gemm_out(
    const bf16_t* __restrict__ A, const bf16_t* __restrict__ W,
    const float* __restrict__ bias, float* __restrict__ C, int M, int N,
    int K) {
  __shared__ __align__(16) char smem[12288];
  bf16_t (*As)[32] = reinterpret_cast<bf16_t(*)[32]>(smem);         // 64x32
  bf16_t (*Bs)[32] = reinterpret_cast<bf16_t(*)[32]>(smem + 4096);  // 128x32

  const int t = threadIdx.x;
  const int w = t >> 6, lane = t & 63;
  const int quad = lane >> 4, l16 = lane & 15;
  const int wr = w >> 1, wc = w & 1;
  const int m0 = blockIdx.x * 64;
  const int n0 = blockIdx.y * 128;
  const int srow = t >> 2;
  const int scol = (t & 3) * 8;

  f32x4 acc[2][4] = {};

  for (int k0 = 0; k0 < K; k0 += 32) {
    async_copy16(&A[(size_t)(m0 + srow) * K + k0 + scol], (char*)smem + t * 16);
    async_copy16(&W[(size_t)(n0 + srow) * K + k0 + scol],
                 (char*)smem + 4096 + t * 16);
    async_copy16(&W[(size_t)(n0 + 64 + srow) * K + k0 + scol],
                 (char*)smem + 8192 + t * 16);
    __syncthreads();

    bf16x8 af[2], bfr[4];
#pragma unroll
    for (int mt = 0; mt < 2; mt++)
      af[mt] = *(const bf16x8*)&As[wr * 32 + mt * 16 + l16][quad * 8];
#pragma unroll
    for (int nt = 0; nt < 4; nt++)
      bfr[nt] = *(const bf16x8*)&Bs[wc * 64 + nt * 16 + l16][quad * 8];
#pragma unroll
    for (int mt = 0; mt < 2; mt++)
#pragma unroll
      for (int nt = 0; nt < 4; nt++)
        acc[mt][nt] = MFMA_BF16(af[mt], bfr[nt], acc[mt][nt], 0, 0, 0);
    __syncthreads();
  }

#pragma unroll
  for (int nt = 0; nt < 4; nt++) {
    const int col = n0 + wc * 64 + nt * 16 + l16;
    const float bb = bias[col];
#pragma unroll
    for (int mt = 0; mt < 2; mt++) {
#pragma unroll
      for (int r = 0; r < 4; r++) {
        const int row = m0 + wr * 32 + mt * 16 + quad * 4 + r;
        C[(size_t)row * N + col] = acc[mt][nt][r] + bb;
      }
    }
  }
}

// ---------------------------------------------------------------------------
// Flash v9 (EXACT — best measured 79.0us).  8 waves, kv-parity split, Nq=2,
// in-register P, two-phase counted-vmcnt schedule:
//   phase A: s_waitcnt vmcnt(2) [own K(i) landed] ; s_barrier ;
//            STAGE(i+1) ; read K ; QK MFMAs (setprio) ; softmax -> pb regs
//   phase B: s_waitcnt vmcnt(4) [own V(i) landed] ; s_barrier ;
//            read V ; PV MFMAs (setprio)
// Prefetch for iter i+1 stays IN FLIGHT across both barriers; last iter
// peeled for the final drain.
// ---------------------------------------------------------------------------
__global__ __launch_bounds__(512, 4) void flash_attn(
    const bf16_t* __restrict__ Qt, const bf16_t* __restrict__ Kt,
    const bf16_t* __restrict__ Vt, bf16_t* __restrict__ O, int L) {
  // linear block id lands on XCD i%8 (round-robin dispatch): 2 heads/XCD.
  const int i = blockIdx.x;
  const int slot = i >> 3;                  // 0..63 within XCD
  const int h = (i & 7) * 2 + (slot >> 5);  // 2 heads per XCD
  const int qblk = slot & 31;

  const int t = threadIdx.x;
  const int w = t >> 6, lane = t & 63;
  const int quad = lane >> 4, l16 = lane & 15;
  const int g = w >> 2;   // kv parity group
  const int ws = w & 3;   // q-pair index within group
  const int tq0 = qblk * 8 + ws * 2;

  __shared__ bf16_t Kst[2][8192];  // 16 KB per buffer (chunk pair)
  __shared__ bf16_t Vst[2][8192];  // 16 KB per buffer

  const size_t hb = (size_t)h * 256 * 1024;  // head base in tiled layouts

  union V8 {
    bf16x8 v8;
    bf16x4 v4[2];
  };

  // persistent Q B-frags (two q-tiles per wave)
  bf16x8 qa[2][2];
#pragma unroll
  for (int qt = 0; qt < 2; qt++)
#pragma unroll
    for (int kc = 0; kc < 2; kc++)
      qa[qt][kc] = *(const bf16x8*)(Qt + hb + (size_t)(tq0 + qt) * 1024 +
                                    kc * 512 + lane * 8);

  // stage chunk pair `mc` (chunks 2mc, 2mc+1): K,K then V,V (order matters
  // for the counted vmcnt waits).
#define STAGE(mc_, buf_)                                                      \
  {                                                                           \
    const size_t pb_ = hb + (size_t)(mc_) * 8192;                             \
    async_copy16(Kt + pb_ + (size_t)t * 8, (char*)&Kst[buf_][0] + w * 1024);  \
    async_copy16(Kt + pb_ + 4096 + (size_t)t * 8,                             \
                 (char*)&Kst[buf_][0] + 8192 + w * 1024);                     \
    async_copy16(Vt + pb_ + (size_t)t * 8, (char*)&Vst[buf_][0] + w * 1024);  \
    async_copy16(Vt + pb_ + 4096 + (size_t)t * 8,                             \
                 (char*)&Vst[buf_][0] + 8192 + w * 1024);                     \
  }

  f32x4 oT[2][4] = {};  // [qt][dkt]
  float ls[2] = {0.f, 0.f};
  const int laneK = lane * 16;
  V8 pb[2][2];

  // phase A body: K reads + QK + softmax (fills pb, ls)
#define PHASE_A(buf_)                                                         \
  {                                                                           \
    const char* Kc = (const char*)&Kst[buf_][0] + g * 8192;                   \
    f32x4 sT[2][4];                                                           \
    __builtin_amdgcn_s_setprio(1);                                            \
    _Pragma("unroll") for (int tt = 0; tt < 4; tt++) {                        \
      const bf16x8 k0 = *(const bf16x8*)(Kc + tt * 2048 + laneK);             \
      const bf16x8 k1 = *(const bf16x8*)(Kc + tt * 2048 + 1024 + laneK);      \
      _Pragma("unroll") for (int qt = 0; qt < 2; qt++) {                      \
        f32x4 z = {0.f, 0.f, 0.f, 0.f};                                       \
        z = MFMA_BF16(k0, qa[qt][0], z, 0, 0, 0);                             \
        z = MFMA_BF16(k1, qa[qt][1], z, 0, 0, 0);                             \
        sT[qt][tt] = z;                                                       \
      }                                                                       \
    }                                                                         \
    __builtin_amdgcn_s_setprio(0);                                            \
    _Pragma("unroll") for (int qt = 0; qt < 2; qt++) {                        \
      _Pragma("unroll") for (int tt = 0; tt < 4; tt++) {                      \
        bf16x4 pk;                                                            \
        float rs = 0.f;                                                       \
        _Pragma("unroll") for (int r = 0; r < 4; r++) {                       \
          const float pv = __builtin_amdgcn_exp2f(sT[qt][tt][r]);             \
          rs += pv;                                                           \
          pk[r] = (bf16_t)pv;                                                 \
        }                                                                     \
        ls[qt] += rs;                                                         \
        pb[qt][tt >> 1].v4[tt & 1] = pk;                                      \
      }                                                                       \
    }                                                                         \
  }

  // phase B body: V reads + PV
#define PHASE_B(buf_)                                                         \
  {                                                                           \
    const char* Vc = (const char*)&Vst[buf_][0] + g * 8192;                   \
    __builtin_amdgcn_s_setprio(1);                                            \
    _Pragma("unroll") for (int dkt = 0; dkt < 4; dkt++) {                     \
      _Pragma("unroll") for (int kvc = 0; kvc < 2; kvc++) {                   \
        const bf16x8 vv =                                                     \
            *(const bf16x8*)(Vc + dkt * 2048 + kvc * 1024 + laneK);           \
        _Pragma("unroll") for (int qt = 0; qt < 2; qt++)                      \
            oT[qt][dkt] = MFMA_BF16(vv, pb[qt][kvc].v8, oT[qt][dkt], 0, 0, 0);\
      }                                                                       \
    }                                                                         \
    __builtin_amdgcn_s_setprio(0);                                            \
  }

  STAGE(0, 0);

  const int NMC = L / 128;  // 32 macro-iters
  for (int mc = 0; mc < NMC - 1; mc++) {
    const int buf = mc & 1;
    asm volatile("s_waitcnt vmcnt(2)" ::: "memory");
    __builtin_amdgcn_s_barrier();
    __builtin_amdgcn_sched_barrier(0);
    STAGE(mc + 1, buf ^ 1);
    PHASE_A(buf);
    asm volatile("s_waitcnt vmcnt(4)" ::: "memory");
    __builtin_amdgcn_s_barrier();
    __builtin_amdgcn_sched_barrier(0);
    PHASE_B(buf);
  }
  {  // peeled last iteration: drain to 0 before the V reads
    const int buf = (NMC - 1) & 1;
    asm volatile("s_waitcnt vmcnt(2)" ::: "memory");
    __builtin_amdgcn_s_barrier();
    __builtin_amdgcn_sched_barrier(0);
    PHASE_A(buf);
    asm volatile("s_waitcnt vmcnt(0)" ::: "memory");
    __builtin_amdgcn_s_barrier();
    __builtin_amdgcn_sched_barrier(0);
    PHASE_B(buf);
  }
#undef STAGE
#undef PHASE_A
#undef PHASE_B

  // cross-group combine: g=1 waves hand partial (oT, ls) to matching g=0
  // wave via LDS scratch (qt0 in Kst, qt1 in Vst; stride 20 floats).
  __syncthreads();
  float* sc0 = (float*)&Kst[0][0];
  float* sc1 = (float*)&Vst[0][0];
  const int sidx = (ws * 64 + lane) * 20;
  if (g == 1) {
#pragma unroll
    for (int dkt = 0; dkt < 4; dkt++) {
      *(f32x4*)(sc0 + sidx + dkt * 4) = oT[0][dkt];
      *(f32x4*)(sc1 + sidx + dkt * 4) = oT[1][dkt];
    }
    sc0[sidx + 16] = ls[0];
    sc1[sidx + 16] = ls[1];
  }
  __syncthreads();
  if (g == 0) {
#pragma unroll
    for (int dkt = 0; dkt < 4; dkt++) {
      oT[0][dkt] += *(const f32x4*)(sc0 + sidx + dkt * 4);
      oT[1][dkt] += *(const f32x4*)(sc1 + sidx + dkt * 4);
    }
    ls[0] += sc0[sidx + 16];
    ls[1] += sc1[sidx + 16];

#pragma unroll
    for (int qt = 0; qt < 2; qt++) {
      float l = ls[qt];
      l += __shfl_xor(l, 16);
      l += __shfl_xor(l, 32);
      const float inv = 1.0f / l;
      const size_t row = (size_t)(tq0 + qt) * 16 + l16;
#pragma unroll
      for (int dkt = 0; dkt < 4; dkt++) {
        bf16x4 ov;
#pragma unroll
        for (int r = 0; r < 4; r++) ov[r] = (bf16_t)(oT[qt][dkt][r] * inv);
        *(bf16x4*)(O + row * 1024 + h * 64 + dkt * 16 + quad * 4) = ov;
      }
    }
  }
}

// ---------------------------------------------------------------------------
extern "C" void kernel_launch(void* const* d_in, const int* in_sizes, int n_in,
                              void* d_out, int out_size, void* d_ws,
                              size_t ws_size, hipStream_t stream) {
  const float* q  = (const float*)d_in[0];
  const float* k  = (const float*)d_in[1];
  const float* v  = (const float*)d_in[2];
  const float* wq = (const float*)d_in[3];
  const float* bq = (const float*)d_in[4];
  const float* wk = (const float*)d_in[5];
  const float* bk = (const float*)d_in[6];
  const float* wv = (const float*)d_in[7];
  const float* bv = (const float*)d_in[8];
  const float* wo = (const float*)d_in[9];
  const float* bo = (const float*)d_in[10];
  float* out = (float*)d_out;

  const int L = 4096, D = 1024;
  const int nLD = L * D;  // 4M
  const int nDD = D * D;  // 1M
  bf16_t* p = (bf16_t*)d_ws;
  bf16_t* qb  = p; p += nLD;
  bf16_t* kb  = p; p += nLD;
  bf16_t* vb  = p; p += nLD;
  bf16_t* wqb = p; p += nDD;
  bf16_t* wkb = p; p += nDD;
  bf16_t* wvb = p; p += nDD;
  bf16_t* wob = p; p += nDD;
  bf16_t* Op  = p; p += nLD;
  bf16_t* Qt  = p; p += nLD;
  bf16_t* Kt  = p; p += nLD;
  bf16_t* Vt  = p; p += nLD;

  dim3 blk(256);
  cast_f32_bf16<<<dim3(nLD / (256 * 8), 1, 7), blk, 0, stream>>>(
      q, qb, nLD, k, kb, nLD, v, vb, nLD, wq, wqb, nDD, wk, wkb, nDD,
      wv, wvb, nDD, wo, wob, nDD);
  gemm_qkv<<<dim3(L / 64, D / 128, 3), blk, 0, stream>>>(
      qb, wqb, bq, Qt, kb, wkb, bk, Kt, vb, wvb, bv, Vt, L, D, D);
  flash_attn<<<dim3((L / 128) * 16), dim3(512), 0, stream>>>(Qt, Kt, Vt, Op, L);
  gemm_out<<<dim3(L / 64, D / 128), blk, 0, stream>>>(Op, wob, bo, out, L, D,
                                                      D);
}

// Round 9
// 247.465 us; speedup vs baseline: 1.1164x; 1.0233x over previous
//
#include <hip/hip_runtime.h>
#include <hip/hip_bf16.h>
#include <stdint.h>

// MHA: B=1, L=4096, D=1024, H=16, dk=64.
// Inputs fp32, OUTPUT fp32. Internal compute bf16 with fp32 accumulation.
//
// v12:
//  - flash: EXACT v9/v11 (best measured 77.7us).  Untouched.
//  - Both GEMMs get the flash-proven staging schedule: LDS double-buffer
//    (2x12KB), STAGE(i+1) issued right after the single per-iter barrier,
//    per-wave vmcnt(0) that waits only for copies issued a FULL ITERATION
//    earlier (latency covered by 8 MFMA + ds_reads), one barrier per iter
//    instead of two.  v11's 2-barrier loop drained just-issued copies every
//    iteration (the m233 ~72% stall structure).
//  - gemm_qkv keeps the v11 64x128 tile + LDS-routed frag-major epilogue
//    (16KB image fits the 24KB dbuf pool after a post-loop barrier).

typedef __bf16 bf16_t;
typedef __bf16 bf16x8 __attribute__((ext_vector_type(8)));
typedef __bf16 bf16x4 __attribute__((ext_vector_type(4)));
typedef float f32x4 __attribute__((ext_vector_type(4)));
typedef unsigned short u16x8 __attribute__((ext_vector_type(8)));

#define MFMA_BF16 __builtin_amdgcn_mfma_f32_16x16x32_bf16

__device__ __forceinline__ void async_copy16(const void* g, void* lds) {
  __builtin_amdgcn_global_load_lds(
      (__attribute__((address_space(1))) void*)(uintptr_t)g,
      (__attribute__((address_space(3))) void*)lds, 16, 0, 0);
}

// ---------------------------------------------------------------------------
// fp32 -> bf16 cast, 8 elems/thread, z selects tensor.
// ---------------------------------------------------------------------------
__global__ __launch_bounds__(256) void cast_f32_bf16(
    const float* __restrict__ s0, bf16_t* __restrict__ d0, int n0,
    const float* __restrict__ s1, bf16_t* __restrict__ d1, int n1,
    const float* __restrict__ s2, bf16_t* __restrict__ d2, int n2,
    const float* __restrict__ s3, bf16_t* __restrict__ d3, int n3,
    const float* __restrict__ s4, bf16_t* __restrict__ d4, int n4,
    const float* __restrict__ s5, bf16_t* __restrict__ d5, int n5,
    const float* __restrict__ s6, bf16_t* __restrict__ d6, int n6) {
  const float* s;
  bf16_t* d;
  int n;
  switch (blockIdx.z) {
    case 0: s = s0; d = d0; n = n0; break;
    case 1: s = s1; d = d1; n = n1; break;
    case 2: s = s2; d = d2; n = n2; break;
    case 3: s = s3; d = d3; n = n3; break;
    case 4: s = s4; d = d4; n = n4; break;
    case 5: s = s5; d = d5; n = n5; break;
    default: s = s6; d = d6; n = n6; break;
  }
  const int i = (blockIdx.x * 256 + threadIdx.x) * 8;
  if (i >= n) return;
  float4 a = *(const float4*)(s + i);
  float4 b = *(const float4*)(s + i + 4);
  bf16x8 o;
  o[0] = (bf16_t)a.x; o[1] = (bf16_t)a.y; o[2] = (bf16_t)a.z; o[3] = (bf16_t)a.w;
  o[4] = (bf16_t)b.x; o[5] = (bf16_t)b.y; o[6] = (bf16_t)b.z; o[7] = (bf16_t)b.w;
  *(bf16x8*)(d + i) = o;
}

// ---------------------------------------------------------------------------
// QKV projection GEMM, tile 64x128, BK=32, 4 waves 2x2, LDS double-buffer
// with stage-ahead + single barrier per iter (flash-v9 discipline).
// z=0 -> Qt (scaled), z=1 -> Kt, z=2 -> Vt (transposed+P-packet-permuted).
// Epilogue: acc -> 16KB LDS image in frag-granule order -> 4 linear passes
// of dwordx4 into the 2 contiguous 8KB regions (v11-verified formulas).
// ---------------------------------------------------------------------------
__global__ __launch_bounds__(256) void gemm_qkv(
    const bf16_t* __restrict__ A0, const bf16_t* __restrict__ W0,
    const float* __restrict__ b0, bf16_t* __restrict__ D0,
    const bf16_t* __restrict__ A1, const bf16_t* __restrict__ W1,
    const float* __restrict__ b1, bf16_t* __restrict__ D1,
    const bf16_t* __restrict__ A2, const bf16_t* __restrict__ W2,
    const float* __restrict__ b2, bf16_t* __restrict__ D2,
    int M, int N, int K) {
  const bf16_t *A, *W;
  const float* bias;
  bf16_t* D;
  const int zz = blockIdx.z;
  if (zz == 0)      { A = A0; W = W0; bias = b0; D = D0; }
  else if (zz == 1) { A = A1; W = W1; bias = b1; D = D1; }
  else              { A = A2; W = W2; bias = b2; D = D2; }

  // buffer b at smem + b*12288: A 64x32 (4KB) then B 128x32 (8KB).
  __shared__ __align__(16) char smem[24576];

  const int t = threadIdx.x;
  const int w = t >> 6, lane = t & 63;
  const int quad = lane >> 4, l16 = lane & 15;
  const int wr = w >> 1, wc = w & 1;
  const int m0 = blockIdx.x * 64;
  const int n0 = blockIdx.y * 128;
  const int srow = t >> 2;       // staging row (4 threads/row)
  const int scol = (t & 3) * 8;  // staging col (elems)

  f32x4 acc[2][4] = {};

#define GSTAGE(k0_, b_)                                                     \
  {                                                                         \
    async_copy16(&A[(size_t)(m0 + srow) * K + (k0_) + scol],                \
                 (char*)smem + (b_) * 12288 + t * 16);                      \
    async_copy16(&W[(size_t)(n0 + srow) * K + (k0_) + scol],                \
                 (char*)smem + (b_) * 12288 + 4096 + t * 16);               \
    async_copy16(&W[(size_t)(n0 + 64 + srow) * K + (k0_) + scol],           \
                 (char*)smem + (b_) * 12288 + 8192 + t * 16);               \
  }

  GSTAGE(0, 0);

  const int NIT = K / 32;  // 32
  for (int i = 0; i < NIT; i++) {
    const int b = i & 1;
    asm volatile("s_waitcnt vmcnt(0)" ::: "memory");  // STAGE(i): full iter old
    __builtin_amdgcn_s_barrier();
    __builtin_amdgcn_sched_barrier(0);
    if (i + 1 < NIT) GSTAGE((i + 1) * 32, b ^ 1);

    const bf16_t(*As)[32] =
        reinterpret_cast<const bf16_t(*)[32]>(smem + b * 12288);
    const bf16_t(*Bs)[32] =
        reinterpret_cast<const bf16_t(*)[32]>(smem + b * 12288 + 4096);

    bf16x8 af[2], bfr[4];
#pragma unroll
    for (int mt = 0; mt < 2; mt++)
      af[mt] = *(const bf16x8*)&As[wr * 32 + mt * 16 + l16][quad * 8];
#pragma unroll
    for (int nt = 0; nt < 4; nt++)
      bfr[nt] = *(const bf16x8*)&Bs[wc * 64 + nt * 16 + l16][quad * 8];
#pragma unroll
    for (int mt = 0; mt < 2; mt++)
#pragma unroll
      for (int nt = 0; nt < 4; nt++)
        acc[mt][nt] = MFMA_BF16(af[mt], bfr[nt], acc[mt][nt], 0, 0, 0);
  }
#undef GSTAGE
  __syncthreads();  // all waves done reading both buffers before Ep overwrite

  // ---- epilogue: dump acc into 16KB LDS image (frag-granule order) ----
  bf16_t* Ep = (bf16_t*)smem;  // [gr 0..7][1024]
  if (zz < 2) {
    const float qs = (zz == 0) ? 0.125f * 1.44269504088896340736f : 1.0f;
#pragma unroll
    for (int nt = 0; nt < 4; nt++) {
      const int col = n0 + wc * 64 + nt * 16 + l16;
      const float bb = bias[col];
      const int dk = nt * 16 + l16;
      const int igb = ((dk >> 5) * 64 + ((dk >> 3) & 3) * 16) * 8 + (dk & 7);
#pragma unroll
      for (int mt = 0; mt < 2; mt++) {
        const int gr = wc * 4 + wr * 2 + mt;  // row-granule within region
#pragma unroll
        for (int r = 0; r < 4; r++)
          Ep[gr * 1024 + igb + (quad * 4 + r) * 8] =
              (bf16_t)((acc[mt][nt][r] + bb) * qs);
      }
    }
  } else {
    // V: kv = m0 + wr*32 + mt*16 + quad*4 + r; granule-within-chunk = nt.
#pragma unroll
    for (int nt = 0; nt < 4; nt++) {
      const int col = n0 + wc * 64 + nt * 16 + l16;
      const float bb = bias[col];
      const int gr = wc * 4 + nt;
#pragma unroll
      for (int mt = 0; mt < 2; mt++) {
        bf16x4 pk;
#pragma unroll
        for (int r = 0; r < 4; r++) pk[r] = (bf16_t)(acc[mt][nt][r] + bb);
        *(bf16x4*)&Ep[gr * 1024 + (wr * 64 + quad * 16 + l16) * 8 + mt * 4] =
            pk;
      }
    }
  }
  __syncthreads();

  // ---- linear copy: 2 contiguous 8KB regions, 16B/lane coalesced ----
  const int hh0 = n0 >> 6;
  const size_t gb = (zz < 2) ? (size_t)(m0 >> 4) : (size_t)(m0 >> 6) * 4;
#pragma unroll
  for (int p = 0; p < 4; p++) {
    const int f = (p * 256 + t) * 8;  // elem index in Ep
    const int reg = f >> 12;          // head-half region
    const int off = f & 4095;
    const float4 vv = *(const float4*)&Ep[f];
    *(float4*)(D + ((size_t)(hh0 + reg) * 256 + gb) * 1024 + off) = vv;
  }
}

// ---------------------------------------------------------------------------
// Output GEMM: C = A @ W^T + b (fp32 out).  Tile 64x128, dbuf stage-ahead.
// ---------------------------------------------------------------------------
__global__ __launch_bounds__(256) void gemm_out(
    const bf16_t* __restrict__ A, const bf16_t* __restrict__ W,
    const float* __restrict__ bias, float* __restrict__ C, int M, int N,
    int K) {
  __shared__ __align__(16) char smem[24576];

  const int t = threadIdx.x;
  const int w = t >> 6, lane = t & 63;
  const int quad = lane >> 4, l16 = lane & 15;
  const int wr = w >> 1, wc = w & 1;
  const int m0 = blockIdx.x * 64;
  const int n0 = blockIdx.y * 128;
  const int srow = t >> 2;
  const int scol = (t & 3) * 8;

  f32x4 acc[2][4] = {};

#define GSTAGE(k0_, b_)                                                     \
  {                                                                         \
    async_copy16(&A[(size_t)(m0 + srow) * K + (k0_) + scol],                \
                 (char*)smem + (b_) * 12288 + t * 16);                      \
    async_copy16(&W[(size_t)(n0 + srow) * K + (k0_) + scol],                \
                 (char*)smem + (b_) * 12288 + 4096 + t * 16);               \
    async_copy16(&W[(size_t)(n0 + 64 + srow) * K + (k0_) + scol],           \
                 (char*)smem + (b_) * 12288 + 8192 + t * 16);               \
  }

  GSTAGE(0, 0);

  const int NIT = K / 32;
  for (int i = 0; i < NIT; i++) {
    const int b = i & 1;
    asm volatile("s_waitcnt vmcnt(0)" ::: "memory");
    __builtin_amdgcn_s_barrier();
    __builtin_amdgcn_sched_barrier(0);
    if (i + 1 < NIT) GSTAGE((i + 1) * 32, b ^ 1);

    const bf16_t(*As)[32] =
        reinterpret_cast<const bf16_t(*)[32]>(smem + b * 12288);
    const bf16_t(*Bs)[32] =
        reinterpret_cast<const bf16_t(*)[32]>(smem + b * 12288 + 4096);

    bf16x8 af[2], bfr[4];
#pragma unroll
    for (int mt = 0; mt < 2; mt++)
      af[mt] = *(const bf16x8*)&As[wr * 32 + mt * 16 + l16][quad * 8];
#pragma unroll
    for (int nt = 0; nt < 4; nt++)
      bfr[nt] = *(const bf16x8*)&Bs[wc * 64 + nt * 16 + l16][quad * 8];
#pragma unroll
    for (int mt = 0; mt < 2; mt++)
#pragma unroll
      for (int nt = 0; nt < 4; nt++)
        acc[mt][nt] = MFMA_BF16(af[mt], bfr[nt], acc[mt][nt], 0, 0, 0);
  }
#undef GSTAGE

#pragma unroll
  for (int nt = 0; nt < 4; nt++) {
    const int col = n0 + wc * 64 + nt * 16 + l16;
    const float bb = bias[col];
#pragma unroll
    for (int mt = 0; mt < 2; mt++) {
#pragma unroll
      for (int r = 0; r < 4; r++) {
        const int row = m0 + wr * 32 + mt * 16 + quad * 4 + r;
        C[(size_t)row * N + col] = acc[mt][nt][r] + bb;
      }
    }
  }
}

// ---------------------------------------------------------------------------
// Flash v9 (EXACT — best measured 77.7us).  8 waves, kv-parity split, Nq=2,
// in-register P, two-phase counted-vmcnt schedule:
//   phase A: s_waitcnt vmcnt(2) [own K(i) landed] ; s_barrier ;
//            STAGE(i+1) ; read K ; QK MFMAs (setprio) ; softmax -> pb regs
//   phase B: s_waitcnt vmcnt(4) [own V(i) landed] ; s_barrier ;
//            read V ; PV MFMAs (setprio)
// Prefetch for iter i+1 stays IN FLIGHT across both barriers; last iter
// peeled for the final drain.
// ---------------------------------------------------------------------------
__global__ __launch_bounds__(512, 4) void flash_attn(
    const bf16_t* __restrict__ Qt, const bf16_t* __restrict__ Kt,
    const bf16_t* __restrict__ Vt, bf16_t* __restrict__ O, int L) {
  // linear block id lands on XCD i%8 (round-robin dispatch): 2 heads/XCD.
  const int i = blockIdx.x;
  const int slot = i >> 3;                  // 0..63 within XCD
  const int h = (i & 7) * 2 + (slot >> 5);  // 2 heads per XCD
  const int qblk = slot & 31;

  const int t = threadIdx.x;
  const int w = t >> 6, lane = t & 63;
  const int quad = lane >> 4, l16 = lane & 15;
  const int g = w >> 2;   // kv parity group
  const int ws = w & 3;   // q-pair index within group
  const int tq0 = qblk * 8 + ws * 2;

  __shared__ bf16_t Kst[2][8192];  // 16 KB per buffer (chunk pair)
  __shared__ bf16_t Vst[2][8192];  // 16 KB per buffer

  const size_t hb = (size_t)h * 256 * 1024;  // head base in tiled layouts

  union V8 {
    bf16x8 v8;
    bf16x4 v4[2];
  };

  // persistent Q B-frags (two q-tiles per wave)
  bf16x8 qa[2][2];
#pragma unroll
  for (int qt = 0; qt < 2; qt++)
#pragma unroll
    for (int kc = 0; kc < 2; kc++)
      qa[qt][kc] = *(const bf16x8*)(Qt + hb + (size_t)(tq0 + qt) * 1024 +
                                    kc * 512 + lane * 8);

  // stage chunk pair `mc` (chunks 2mc, 2mc+1): K,K then V,V (order matters
  // for the counted vmcnt waits).
#define STAGE(mc_, buf_)                                                      \
  {                                                                           \
    const size_t pb_ = hb + (size_t)(mc_) * 8192;                             \
    async_copy16(Kt + pb_ + (size_t)t * 8, (char*)&Kst[buf_][0] + w * 1024);  \
    async_copy16(Kt + pb_ + 4096 + (size_t)t * 8,                             \
                 (char*)&Kst[buf_][0] + 8192 + w * 1024);                     \
    async_copy16(Vt + pb_ + (size_t)t * 8, (char*)&Vst[buf_][0] + w * 1024);  \
    async_copy16(Vt + pb_ + 4096 + (size_t)t * 8,                             \
                 (char*)&Vst[buf_][0] + 8192 + w * 1024);                     \
  }

  f32x4 oT[2][4] = {};  // [qt][dkt]
  float ls[2] = {0.f, 0.f};
  const int laneK = lane * 16;
  V8 pb[2][2];

  // phase A body: K reads + QK + softmax (fills pb, ls)
#define PHASE_A(buf_)                                                         \
  {                                                                           \
    const char* Kc = (const char*)&Kst[buf_][0] + g * 8192;                   \
    f32x4 sT[2][4];                                                           \
    __builtin_amdgcn_s_setprio(1);                                            \
    _Pragma("unroll") for (int tt = 0; tt < 4; tt++) {                        \
      const bf16x8 k0 = *(const bf16x8*)(Kc + tt * 2048 + laneK);             \
      const bf16x8 k1 = *(const bf16x8*)(Kc + tt * 2048 + 1024 + laneK);      \
      _Pragma("unroll") for (int qt = 0; qt < 2; qt++) {                      \
        f32x4 z = {0.f, 0.f, 0.f, 0.f};                                       \
        z = MFMA_BF16(k0, qa[qt][0], z, 0, 0, 0);                             \
        z = MFMA_BF16(k1, qa[qt][1], z, 0, 0, 0);                             \
        sT[qt][tt] = z;                                                       \
      }                                                                       \
    }                                                                         \
    __builtin_amdgcn_s_setprio(0);                                            \
    _Pragma("unroll") for (int qt = 0; qt < 2; qt++) {                        \
      _Pragma("unroll") for (int tt = 0; tt < 4; tt++) {                      \
        bf16x4 pk;                                                            \
        float rs = 0.f;                                                       \
        _Pragma("unroll") for (int r = 0; r < 4; r++) {                       \
          const float pv = __builtin_amdgcn_exp2f(sT[qt][tt][r]);             \
          rs += pv;                                                           \
          pk[r] = (bf16_t)pv;                                                 \
        }                                                                     \
        ls[qt] += rs;                                                         \
        pb[qt][tt >> 1].v4[tt & 1] = pk;                                      \
      }                                                                       \
    }                                                                         \
  }

  // phase B body: V reads + PV
#define PHASE_B(buf_)                                                         \
  {                                                                           \
    const char* Vc = (const char*)&Vst[buf_][0] + g * 8192;                   \
    __builtin_amdgcn_s_setprio(1);                                            \
    _Pragma("unroll") for (int dkt = 0; dkt < 4; dkt++) {                     \
      _Pragma("unroll") for (int kvc = 0; kvc < 2; kvc++) {                   \
        const bf16x8 vv =                                                     \
            *(const bf16x8*)(Vc + dkt * 2048 + kvc * 1024 + laneK);           \
        _Pragma("unroll") for (int qt = 0; qt < 2; qt++)                      \
            oT[qt][dkt] = MFMA_BF16(vv, pb[qt][kvc].v8, oT[qt][dkt], 0, 0, 0);\
      }                                                                       \
    }                                                                         \
    __builtin_amdgcn_s_setprio(0);                                            \
  }

  STAGE(0, 0);

  const int NMC = L / 128;  // 32 macro-iters
  for (int mc = 0; mc < NMC - 1; mc++) {
    const int buf = mc & 1;
    asm volatile("s_waitcnt vmcnt(2)" ::: "memory");
    __builtin_amdgcn_s_barrier();
    __builtin_amdgcn_sched_barrier(0);
    STAGE(mc + 1, buf ^ 1);
    PHASE_A(buf);
    asm volatile("s_waitcnt vmcnt(4)" ::: "memory");
    __builtin_amdgcn_s_barrier();
    __builtin_amdgcn_sched_barrier(0);
    PHASE_B(buf);
  }
  {  // peeled last iteration: drain to 0 before the V reads
    const int buf = (NMC - 1) & 1;
    asm volatile("s_waitcnt vmcnt(2)" ::: "memory");
    __builtin_amdgcn_s_barrier();
    __builtin_amdgcn_sched_barrier(0);
    PHASE_A(buf);
    asm volatile("s_waitcnt vmcnt(0)" ::: "memory");
    __builtin_amdgcn_s_barrier();
    __builtin_amdgcn_sched_barrier(0);
    PHASE_B(buf);
  }
#undef STAGE
#undef PHASE_A
#undef PHASE_B

  // cross-group combine: g=1 waves hand partial (oT, ls) to matching g=0
  // wave via LDS scratch (qt0 in Kst, qt1 in Vst; stride 20 floats).
  __syncthreads();
  float* sc0 = (float*)&Kst[0][0];
  float* sc1 = (float*)&Vst[0][0];
  const int sidx = (ws * 64 + lane) * 20;
  if (g == 1) {
#pragma unroll
    for (int dkt = 0; dkt < 4; dkt++) {
      *(f32x4*)(sc0 + sidx + dkt * 4) = oT[0][dkt];
      *(f32x4*)(sc1 + sidx + dkt * 4) = oT[1][dkt];
    }
    sc0[sidx + 16] = ls[0];
    sc1[sidx + 16] = ls[1];
  }
  __syncthreads();
  if (g == 0) {
#pragma unroll
    for (int dkt = 0; dkt < 4; dkt++) {
      oT[0][dkt] += *(const f32x4*)(sc0 + sidx + dkt * 4);
      oT[1][dkt] += *(const f32x4*)(sc1 + sidx + dkt * 4);
    }
    ls[0] += sc0[sidx + 16];
    ls[1] += sc1[sidx + 16];

#pragma unroll
    for (int qt = 0; qt < 2; qt++) {
      float l = ls[qt];
      l += __shfl_xor(l, 16);
      l += __shfl_xor(l, 32);
      const float inv = 1.0f / l;
      const size_t row = (size_t)(tq0 + qt) * 16 + l16;
#pragma unroll
      for (int dkt = 0; dkt < 4; dkt++) {
        bf16x4 ov;
#pragma unroll
        for (int r = 0; r < 4; r++) ov[r] = (bf16_t)(oT[qt][dkt][r] * inv);
        *(bf16x4*)(O + row * 1024 + h * 64 + dkt * 16 + quad * 4) = ov;
      }
    }
  }
}

// ---------------------------------------------------------------------------
extern "C" void kernel_launch(void* const* d_in, const int* in_sizes, int n_in,
                              void* d_out, int out_size, void* d_ws,
                              size_t ws_size, hipStream_t stream) {
  const float* q  = (const float*)d_in[0];
  const float* k  = (const float*)d_in[1];
  const float* v  = (const float*)d_in[2];
  const float* wq = (const float*)d_in[3];
  const float* bq = (const float*)d_in[4];
  const float* wk = (const float*)d_in[5];
  const float* bk = (const float*)d_in[6];
  const float* wv = (const float*)d_in[7];
  const float* bv = (const float*)d_in[8];
  const float* wo = (const float*)d_in[9];
  const float* bo = (const float*)d_in[10];
  float* out = (float*)d_out;

  const int L = 4096, D = 1024;
  const int nLD = L * D;  // 4M
  const int nDD = D * D;  // 1M
  bf16_t* p = (bf16_t*)d_ws;
  bf16_t* qb  = p; p += nLD;
  bf16_t* kb  = p; p += nLD;
  bf16_t* vb  = p; p += nLD;
  bf16_t* wqb = p; p += nDD;
  bf16_t* wkb = p; p += nDD;
  bf16_t* wvb = p; p += nDD;
  bf16_t* wob = p; p += nDD;
  bf16_t* Op  = p; p += nLD;
  bf16_t* Qt  = p; p += nLD;
  bf16_t* Kt  = p; p += nLD;
  bf16_t* Vt  = p; p += nLD;

  dim3 blk(256);
  cast_f32_bf16<<<dim3(nLD / (256 * 8), 1, 7), blk, 0, stream>>>(
      q, qb, nLD, k, kb, nLD, v, vb, nLD, wq, wqb, nDD, wk, wkb, nDD,
      wv, wvb, nDD, wo, wob, nDD);
  gemm_qkv<<<dim3(L / 64, D / 128, 3), blk, 0, stream>>>(
      qb, wqb, bq, Qt, kb, wkb, bk, Kt, vb, wvb, bv, Vt, L, D, D);
  flash_attn<<<dim3((L / 128) * 16), dim3(512), 0, stream>>>(Qt, Kt, Vt, Op, L);
  gemm_out<<<dim3(L / 64, D / 128), blk, 0, stream>>>(Op, wob, bo, out, L, D,
                                                      D);
}